// Round 8
// baseline (4699.377 us; speedup 1.0000x reference)
//
#include <hip/hip_runtime.h>
#include <stdint.h>

// ---- problem constants ----
constexpr int HD   = 512;
constexpr int TS   = 256;
constexpr int NB   = 64;
constexpr int MBR  = 128;
constexpr int SLAB = MBR * HD;   // 65536 elements per h-slab

typedef __attribute__((ext_vector_type(8))) short bf16x8;
typedef __attribute__((ext_vector_type(4))) float f32x4;

__device__ __forceinline__ unsigned short f2bf(float f){
  union { float f; unsigned u; } v; v.f = f;
  unsigned r = v.u + 0x7fffu + ((v.u >> 16) & 1u);
  return (unsigned short)(r >> 16);
}
__device__ __forceinline__ float fsig(float x){ return 1.f / (1.f + __expf(-x)); }
__device__ __forceinline__ float ftanh(float x){ return 1.f - 2.f / (__expf(2.f * x) + 1.f); }
__device__ __forceinline__ void vdrain(){ asm volatile("s_waitcnt vmcnt(0)" ::: "memory"); }

__device__ __forceinline__ int ld_sc0(const int* p){
  int v; asm volatile("global_load_dword %0, %1, off sc0\n\ts_waitcnt vmcnt(0)"
                      : "=v"(v) : "v"(p) : "memory"); return v;
}
__device__ __forceinline__ int ld_sc1(const int* p){
  int v; asm volatile("global_load_dword %0, %1, off sc0 sc1\n\ts_waitcnt vmcnt(0)"
                      : "=v"(v) : "v"(p) : "memory"); return v;
}
__device__ __forceinline__ void st_sc1(void* p, int v){
  asm volatile("global_store_dword %0, %1, off sc0 sc1" :: "v"(p), "v"(v) : "memory");
}
__device__ __forceinline__ f32x4 ld16_sc0_one(const void* p){
  f32x4 v; asm volatile("global_load_dwordx4 %0, %1, off sc0"
                        : "=&v"(v) : "v"(p) : "memory"); return v;
}
// 16 x 16B sc1 loads (one A-row, K=512), single trailing waitcnt. R6-proven.
__device__ __forceinline__ void ld16_sc1(const void* p, f32x4* r){
  asm volatile(
    "global_load_dwordx4 %0,  %16, off sc0 sc1\n\t"
    "global_load_dwordx4 %1,  %16, off offset:64 sc0 sc1\n\t"
    "global_load_dwordx4 %2,  %16, off offset:128 sc0 sc1\n\t"
    "global_load_dwordx4 %3,  %16, off offset:192 sc0 sc1\n\t"
    "global_load_dwordx4 %4,  %16, off offset:256 sc0 sc1\n\t"
    "global_load_dwordx4 %5,  %16, off offset:320 sc0 sc1\n\t"
    "global_load_dwordx4 %6,  %16, off offset:384 sc0 sc1\n\t"
    "global_load_dwordx4 %7,  %16, off offset:448 sc0 sc1\n\t"
    "global_load_dwordx4 %8,  %16, off offset:512 sc0 sc1\n\t"
    "global_load_dwordx4 %9,  %16, off offset:576 sc0 sc1\n\t"
    "global_load_dwordx4 %10, %16, off offset:640 sc0 sc1\n\t"
    "global_load_dwordx4 %11, %16, off offset:704 sc0 sc1\n\t"
    "global_load_dwordx4 %12, %16, off offset:768 sc0 sc1\n\t"
    "global_load_dwordx4 %13, %16, off offset:832 sc0 sc1\n\t"
    "global_load_dwordx4 %14, %16, off offset:896 sc0 sc1\n\t"
    "global_load_dwordx4 %15, %16, off offset:960 sc0 sc1\n\t"
    "s_waitcnt vmcnt(0)"
    : "=&v"(r[0]), "=&v"(r[1]), "=&v"(r[2]), "=&v"(r[3]),
      "=&v"(r[4]), "=&v"(r[5]), "=&v"(r[6]), "=&v"(r[7]),
      "=&v"(r[8]), "=&v"(r[9]), "=&v"(r[10]), "=&v"(r[11]),
      "=&v"(r[12]), "=&v"(r[13]), "=&v"(r[14]), "=&v"(r[15])
    : "v"(p) : "memory");
}
__device__ __forceinline__ bf16x8 pack8(float4 a, float4 b){
  bf16x8 w;
  w[0]=(short)f2bf(a.x); w[1]=(short)f2bf(a.y); w[2]=(short)f2bf(a.z); w[3]=(short)f2bf(a.w);
  w[4]=(short)f2bf(b.x); w[5]=(short)f2bf(b.y); w[6]=(short)f2bf(b.z); w[7]=(short)f2bf(b.w);
  return w;
}

// Persistent pipelined 2-layer LSTM.
// 256 WGs x 512 thr, 1 WG/CU. Role via HW_REG_XCC_ID claim (R6-proven):
//   layer = xcd&1, grp = xcd>>1 (32 batch rows), slice = claim idx (16 units).
// LDS: h-tile 32KB (staged per step, swizzled) + recurrent-W 64KB (swizzled).
// Input-projection W: 64 VGPRs/lane.
// Local sync (R6-proven): plain h stores -> vmcnt -> barrier -> per-slice
//   volatile flag store; consumers poll 32 flags with sc0 loads.
// Cross L0->L1 (R6-proven): sc1 h0x stores + sc1 flags; consumer reads h0x
//   via sc1 batched loads; poll amortized to every 4 steps (flags monotone).
__global__ __launch_bounds__(512, 1)
void lstm_persist(const float* __restrict__ text,
                  const float* __restrict__ Wih0, const float* __restrict__ Whh0,
                  const float* __restrict__ bih0, const float* __restrict__ bhh0,
                  const float* __restrict__ Wih1, const float* __restrict__ Whh1,
                  const float* __restrict__ bih1, const float* __restrict__ bhh1,
                  unsigned short* __restrict__ h0r,   // [4][128][512] local ring
                  unsigned short* __restrict__ h0x,   // [256][128][512] cross, full depth
                  unsigned short* __restrict__ h1r,   // [4][128][512] local ring
                  float* __restrict__ H1f,            // [128][512] final h1 fp32
                  int* __restrict__ F0loc,            // [4][256][32] local flags L0
                  int* __restrict__ F1loc,            // [4][256][32] local flags L1
                  int* __restrict__ F0x,              // [4][256][32] cross flags
                  unsigned* __restrict__ claim)       // [8] per-XCD claim counters
{
  extern __shared__ char lds[];        // 0..32767: h-tile, 32768..98303: Wpost
  char* Atile = lds;
  char* Wpost = lds + 32768;
  __shared__ int s_role;

  const int tid = threadIdx.x;
  if (tid == 0){
    unsigned xcc;
    asm volatile("s_getreg_b32 %0, hwreg(HW_REG_XCC_ID)" : "=s"(xcc));
    xcc &= 7u;
    unsigned idx = __hip_atomic_fetch_add(claim + xcc, 1u,
                     __ATOMIC_RELAXED, __HIP_MEMORY_SCOPE_AGENT);
    s_role = (int)((xcc << 5) | (idx & 31u));
  }
  __syncthreads();
  const int role  = s_role;
  const int xcd   = role >> 5;
  const int layer = xcd & 1;
  const int grp   = xcd >> 1;
  const int slice = role & 31;
  const int m0    = grp * 32;
  const int u0    = slice * 16;
  const int wv    = tid >> 6;
  const int l     = tid & 63;
  const int lj    = l & 15;
  const int lk    = l >> 4;
  const int wgrp  = wv & 3;
  const int mi    = wv >> 2;

  int* F0l  = F0loc + grp * (TS * 32);
  int* F1l  = F1loc + grp * (TS * 32);
  int* F0xg = F0x   + grp * (TS * 32);

  const float* Wihl = layer ? Wih1 : Wih0;
  const float* Whhl = layer ? Whh1 : Whh0;

  // ---- one-time: recurrent weights -> LDS (f32 -> bf16, swizzled) ----
  for (int it = tid; it < 4096; it += 512){
    int c = it >> 6, gk = it & 63;                      // col 0..63, granule 0..63
    int unit = u0 + ((c >> 4) << 2) + ((c & 15) >> 2);
    int gate = c & 3;
    const float* s = Whhl + (size_t)(gate * HD + unit) * HD + gk * 8;
    *(bf16x8*)(Wpost + c * 1024 + ((gk ^ (c & 7)) << 4)) =
        pack8(((const float4*)s)[0], ((const float4*)s)[1]);
  }
  // ---- one-time: input-projection weights -> registers (64 VGPR) ----
  const int myunit = u0 + (wgrp << 2) + (lj >> 2);
  const int mygate = lj & 3;
  bf16x8 bPre[16];
  {
    const float* s0 = Wihl + (size_t)(mygate * HD + myunit) * HD + lk * 8;
    #pragma unroll
    for (int kk = 0; kk < 16; ++kk){
      const float* s = s0 + kk * 32;
      bPre[kk] = pack8(((const float4*)s)[0], ((const float4*)s)[1]);
    }
  }
  const float bgv = (layer ? bih1 : bih0)[mygate * HD + myunit]
                  + (layer ? bhh1 : bhh0)[mygate * HD + myunit];

  const int arow_b = (mi * 16 + lj) * 1024;   // A-tile row byte base
  const int cb     = (wgrp * 16 + lj) * 1024; // W-post col byte base
  const int swz    = lj & 7;

  float cst[4] = {0.f, 0.f, 0.f, 0.f};
  unsigned xp[4];
  __syncthreads();   // LDS weights staged

  // poll 32 local flags via sc0 (lanes 0..31; 32..63 mirror) — R6-proven
  auto poll32 = [&](const int* base){
    const int* fp = base + (l & 31);
    for (;;){
      int v = ld_sc0(fp);
      if (__all(v != 0)) break;
      __builtin_amdgcn_s_sleep(1);
    }
  };
  // poll 32 cross flags via sc1 — R6-proven
  auto pollX32 = [&](const int* base){
    const int* fp = base + (l & 31);
    for (;;){
      int v = ld_sc1(fp);
      if (__all(v != 0)) break;
      __builtin_amdgcn_s_sleep(1);
    }
  };
  // stage h tile (32 rows x 512) global(sc0) -> LDS swizzled
  auto stageTile = [&](const unsigned short* src){
    const int srow = tid >> 4, c16 = tid & 15;
    const char* gp = (const char*)(src + (size_t)(m0 + srow) * HD);
    f32x4 t0 = ld16_sc0_one(gp + (0 * 16 + c16) * 16);
    f32x4 t1 = ld16_sc0_one(gp + (1 * 16 + c16) * 16);
    f32x4 t2 = ld16_sc0_one(gp + (2 * 16 + c16) * 16);
    f32x4 t3 = ld16_sc0_one(gp + (3 * 16 + c16) * 16);
    vdrain();
    char* rb = Atile + srow * 1024;
    const int rs = srow & 7;
    *(f32x4*)(rb + (((0 * 16 + c16) ^ rs) << 4)) = t0;
    *(f32x4*)(rb + (((1 * 16 + c16) ^ rs) << 4)) = t1;
    *(f32x4*)(rb + (((2 * 16 + c16) ^ rs) << 4)) = t2;
    *(f32x4*)(rb + (((3 * 16 + c16) ^ rs) << 4)) = t3;
  };
  // recurrent half from LDS (A-tile x Wpost)
  auto postHalf = [&](f32x4& acc){
    #pragma unroll
    for (int kk = 0; kk < 16; ++kk){
      int g = (kk << 2) + lk;
      bf16x8 a = *(const bf16x8*)(Atile + arow_b + ((g ^ swz) << 4));
      bf16x8 b = *(const bf16x8*)(Wpost + cb + ((g ^ swz) << 4));
      acc = __builtin_amdgcn_mfma_f32_16x16x32_bf16(a, b, acc, 0, 0, 0);
    }
  };
  // L0 input projection: text f32 direct, cvt in-flight
  auto preX = [&](int t, f32x4& acc){
    int ar = m0 + mi * 16 + lj;
    int b  = ar & 63;
    int ts = (ar < 64) ? t : (TS - 1 - t);
    const float* src = text + ((size_t)b * TS + ts) * HD + lk * 8;
    acc = (f32x4){0.f, 0.f, 0.f, 0.f};
    #pragma unroll
    for (int kk = 0; kk < 16; ++kk){
      const float* s = src + kk * 32;
      bf16x8 a = pack8(((const float4*)s)[0], ((const float4*)s)[1]);
      acc = __builtin_amdgcn_mfma_f32_16x16x32_bf16(a, bPre[kk], acc, 0, 0, 0);
    }
  };
  // L1 input projection: h0x via sc1 batched loads (R6-proven read path)
  auto preH0 = [&](int t, f32x4& acc){
    const unsigned short* src = h0x + (size_t)t * SLAB
                              + (size_t)(m0 + mi * 16 + lj) * HD + lk * 8;
    f32x4 raw[16];
    ld16_sc1(src, raw);
    acc = (f32x4){0.f, 0.f, 0.f, 0.f};
    #pragma unroll
    for (int kk = 0; kk < 16; ++kk)
      acc = __builtin_amdgcn_mfma_f32_16x16x32_bf16(
              __builtin_bit_cast(bf16x8, raw[kk]), bPre[kk], acc, 0, 0, 0);
  };
  // cell update; plain local h store; xp[] = packed cross dwords (L0)
  auto cell = [&](const f32x4& aP, const f32x4& aQ,
                  unsigned short* __restrict__ hout, bool wrF){
    #pragma unroll
    for (int r = 0; r < 4; ++r){
      float v  = aP[r] + aQ[r] + bgv;
      float v1 = __shfl_xor(v, 1);
      float v2 = __shfl_xor(v, 2);
      float v3 = __shfl_xor(v, 3);
      auto pick = [&](int m)->float {
        return m == 0 ? v : (m == 1 ? v1 : (m == 2 ? v2 : v3));
      };
      float gi = pick(mygate);
      float gf = pick(mygate ^ 1);
      float gg = pick(mygate ^ 2);
      float go = pick(mygate ^ 3);
      float i_ = fsig(gi);
      float f_ = fsig(gf);
      float g_ = ftanh(gg);
      float o_ = fsig(go);
      float c  = f_ * cst[r] + i_ * g_;
      cst[r] = c;
      float h  = o_ * ftanh(c);
      int row  = m0 + mi * 16 + lk * 4 + r;
      int hb   = (int)f2bf(h);
      int pb   = __shfl_xor(hb, 4);          // partner unit (myunit+1)
      xp[r]    = (unsigned)((hb & 0xffff) | (pb << 16));
      if (mygate == 0){
        hout[(size_t)row * HD + myunit] = (unsigned short)hb;
        if (wrF) H1f[(size_t)row * HD + myunit] = h;
      }
    }
  };

  if (layer == 0){
    // ================= layer 0: free-running =================
    f32x4 accPre;
    preX(0, accPre);
    for (int t = 0; t < TS; ++t){
      f32x4 accPost = {0.f, 0.f, 0.f, 0.f};
      if (t > 0){
        if (wv == 0) poll32(F0l + (t - 1) * 32);
        __syncthreads();
        stageTile(h0r + (size_t)((t - 1) & 3) * SLAB);
        __syncthreads();
        postHalf(accPost);
      }
      cell(accPre, accPost, h0r + (size_t)(t & 3) * SLAB, false);
      vdrain();                 // local h stores visible in L2
      __syncthreads();
      if (tid == 0) *(volatile int*)(F0l + t * 32 + slice) = 1;   // local release
      // cross publish (off local critical path) + next input projection
      if ((lj & 7) == 0){
        char* hx = (char*)(h0x + (size_t)t * SLAB);
        #pragma unroll
        for (int r = 0; r < 4; ++r){
          int row = m0 + mi * 16 + lk * 4 + r;
          st_sc1(hx + ((size_t)row * HD + myunit) * 2, (int)xp[r]);
        }
      }
      if (t + 1 < TS) preX(t + 1, accPre);
      vdrain();                 // h0x stores acked at L3
      __syncthreads();
      if (tid == 0) st_sc1(F0xg + t * 32 + slice, 1);             // cross release
    }
  } else {
    // ================= layer 1: chases L0 =================
    int G = 3;
    f32x4 accPre;
    if (wv == 0) pollX32(F0xg + G * 32);    // covers t=0..3
    __syncthreads();
    preH0(0, accPre);
    for (int t = 0; t < TS; ++t){
      f32x4 accPost = {0.f, 0.f, 0.f, 0.f};
      if (t > 0){
        if (wv == 0) poll32(F1l + (t - 1) * 32);
        __syncthreads();
        stageTile(h1r + (size_t)((t - 1) & 3) * SLAB);
        __syncthreads();
        postHalf(accPost);
      }
      cell(accPre, accPost, h1r + (size_t)(t & 3) * SLAB, t == TS - 1);
      vdrain();
      __syncthreads();
      if (tid == 0) *(volatile int*)(F1l + t * 32 + slice) = 1;
      if (t + 1 < TS){
        const int tn = t + 1;
        if (tn > G){            // amortized cross poll (flags monotone per producer)
          int P = tn + 3; if (P > TS - 1) P = TS - 1;
          if (wv == 0) pollX32(F0xg + P * 32);
          __syncthreads();
          G = P;
        }
        preH0(tn, accPre);
      }
    }
  }
}

// out[b] = dot(h1_fwd[b], Wlin[0:512]) + dot(h1_rev[b], Wlin[512:1024]) + blin
__global__ void final_linear(const float* __restrict__ H1f, const float* __restrict__ Wlin,
                             const float* __restrict__ blin, float* __restrict__ out){
  int b = blockIdx.x, l = threadIdx.x;
  float s = 0.f;
  for (int j = l; j < HD; j += 64) s += H1f[(size_t)b * HD + j]        * Wlin[j];
  for (int j = l; j < HD; j += 64) s += H1f[(size_t)(NB + b) * HD + j] * Wlin[HD + j];
  #pragma unroll
  for (int off = 32; off; off >>= 1) s += __shfl_down(s, off);
  if (l == 0) out[b] = s + blin[0];
}

extern "C" void kernel_launch(void* const* d_in, const int* in_sizes, int n_in,
                              void* d_out, int out_size, void* d_ws, size_t ws_size,
                              hipStream_t stream)
{
  const float* text = (const float*)d_in[0];
  const float* Wih0 = (const float*)d_in[1];
  const float* Whh0 = (const float*)d_in[2];
  const float* bih0 = (const float*)d_in[3];
  const float* bhh0 = (const float*)d_in[4];
  const float* Wih1 = (const float*)d_in[5];
  const float* Whh1 = (const float*)d_in[6];
  const float* bih1 = (const float*)d_in[7];
  const float* bhh1 = (const float*)d_in[8];
  const float* Wlin = (const float*)d_in[9];
  const float* blin = (const float*)d_in[10];

  // ---- ws layout (~34 MiB) ----
  uint8_t* p = (uint8_t*)d_ws;
  unsigned short* h0r = (unsigned short*)p; p += (size_t)4 * SLAB * 2;      // 512 KiB
  unsigned short* h1r = (unsigned short*)p; p += (size_t)4 * SLAB * 2;      // 512 KiB
  float* H1f          = (float*)p;          p += (size_t)SLAB * 4;          // 256 KiB
  unsigned short* h0x = (unsigned short*)p; p += (size_t)TS * SLAB * 2;     // 32 MiB
  int* F0loc          = (int*)p;            p += (size_t)4 * TS * 32 * 4;   // 128 KiB
  int* F1loc          = (int*)p;            p += (size_t)4 * TS * 32 * 4;   // 128 KiB
  int* F0x            = (int*)p;            p += (size_t)4 * TS * 32 * 4;   // 128 KiB
  unsigned* claim     = (unsigned*)p;       p += 256;

  // deterministic init: all flags + claim zero at kernel start (contiguous)
  hipMemsetAsync(F0loc, 0, (size_t)12 * TS * 32 * 4 + 256, stream);

  hipFuncSetAttribute((const void*)lstm_persist,
                      hipFuncAttributeMaxDynamicSharedMemorySize, 98304);

  const float* A0 = text;
  const float *A1 = Wih0, *A2 = Whh0, *A3 = bih0, *A4 = bhh0;
  const float *A5 = Wih1, *A6 = Whh1, *A7 = bih1, *A8 = bhh1;
  unsigned short* B0 = h0r; unsigned short* B1 = h0x; unsigned short* B2 = h1r;
  float* B3 = H1f; int* B4 = F0loc; int* B5 = F1loc; int* B6 = F0x; unsigned* B7 = claim;
  void* args[] = {(void*)&A0,
                  (void*)&A1, (void*)&A2, (void*)&A3, (void*)&A4,
                  (void*)&A5, (void*)&A6, (void*)&A7, (void*)&A8,
                  (void*)&B0, (void*)&B1, (void*)&B2, (void*)&B3,
                  (void*)&B4, (void*)&B5, (void*)&B6, (void*)&B7};
  hipLaunchCooperativeKernel((void*)lstm_persist, dim3(256), dim3(512),
                             args, 98304, stream);

  final_linear<<<NB, 64, 0, stream>>>(H1f, Wlin, blin, (float*)d_out);
}

// Round 12
// 3722.104 us; speedup vs baseline: 1.2626x; 1.2626x over previous
//
#include <hip/hip_runtime.h>
#include <stdint.h>

// ---- problem constants ----
constexpr int HD   = 512;
constexpr int TS   = 256;
constexpr int NB   = 64;
constexpr int MBR  = 128;
constexpr int SLAB = MBR * HD;   // 65536 elements per h-slab

typedef __attribute__((ext_vector_type(8))) short bf16x8;
typedef __attribute__((ext_vector_type(4))) float f32x4;

__device__ __forceinline__ unsigned short f2bf(float f){
  union { float f; unsigned u; } v; v.f = f;
  unsigned r = v.u + 0x7fffu + ((v.u >> 16) & 1u);
  return (unsigned short)(r >> 16);
}
__device__ __forceinline__ float fsig(float x){ return 1.f / (1.f + __expf(-x)); }
__device__ __forceinline__ float ftanh(float x){ return 1.f - 2.f / (__expf(2.f * x) + 1.f); }
__device__ __forceinline__ void vdrain(){ asm volatile("s_waitcnt vmcnt(0)" ::: "memory"); }

// device-scope (memory-side, placement-independent) flag ops — R6/R8-proven
__device__ __forceinline__ int ld_flag_sc1(const int* p){
  int v;
  asm volatile("global_load_dword %0, %1, off sc0 sc1\n\ts_waitcnt vmcnt(0)"
               : "=v"(v) : "v"(p) : "memory");
  return v;
}
__device__ __forceinline__ void st_sc1_b32(void* p, int v){
  asm volatile("global_store_dword %0, %1, off sc0 sc1" :: "v"(p), "v"(v) : "memory");
}

// 16 x 16B sc1 loads (one A-row K-half, 256B/lane). R6/R8-proven pattern.
#define LD16_DEF(NAME, TAIL)                                                    \
__device__ __forceinline__ void NAME(const void* p, f32x4* r){                  \
  asm volatile(                                                                 \
    "global_load_dwordx4 %0,  %16, off sc0 sc1\n\t"                             \
    "global_load_dwordx4 %1,  %16, off offset:64 sc0 sc1\n\t"                   \
    "global_load_dwordx4 %2,  %16, off offset:128 sc0 sc1\n\t"                  \
    "global_load_dwordx4 %3,  %16, off offset:192 sc0 sc1\n\t"                  \
    "global_load_dwordx4 %4,  %16, off offset:256 sc0 sc1\n\t"                  \
    "global_load_dwordx4 %5,  %16, off offset:320 sc0 sc1\n\t"                  \
    "global_load_dwordx4 %6,  %16, off offset:384 sc0 sc1\n\t"                  \
    "global_load_dwordx4 %7,  %16, off offset:448 sc0 sc1\n\t"                  \
    "global_load_dwordx4 %8,  %16, off offset:512 sc0 sc1\n\t"                  \
    "global_load_dwordx4 %9,  %16, off offset:576 sc0 sc1\n\t"                  \
    "global_load_dwordx4 %10, %16, off offset:640 sc0 sc1\n\t"                  \
    "global_load_dwordx4 %11, %16, off offset:704 sc0 sc1\n\t"                  \
    "global_load_dwordx4 %12, %16, off offset:768 sc0 sc1\n\t"                  \
    "global_load_dwordx4 %13, %16, off offset:832 sc0 sc1\n\t"                  \
    "global_load_dwordx4 %14, %16, off offset:896 sc0 sc1\n\t"                  \
    "global_load_dwordx4 %15, %16, off offset:960 sc0 sc1\n\t"                  \
    TAIL                                                                        \
    : "=&v"(r[0]), "=&v"(r[1]), "=&v"(r[2]), "=&v"(r[3]),                       \
      "=&v"(r[4]), "=&v"(r[5]), "=&v"(r[6]), "=&v"(r[7]),                       \
      "=&v"(r[8]), "=&v"(r[9]), "=&v"(r[10]), "=&v"(r[11]),                     \
      "=&v"(r[12]), "=&v"(r[13]), "=&v"(r[14]), "=&v"(r[15])                    \
    : "v"(p) : "memory");                                                       \
}
LD16_DEF(ld16_sc1,       "s_waitcnt vmcnt(0)")
LD16_DEF(ld16_sc1_issue, "s_nop 0")            // issue-only; a later vmcnt(0) drains

__device__ __forceinline__ bf16x8 pack8(float4 a, float4 b){
  bf16x8 w;
  w[0]=(short)f2bf(a.x); w[1]=(short)f2bf(a.y); w[2]=(short)f2bf(a.z); w[3]=(short)f2bf(a.w);
  w[4]=(short)f2bf(b.x); w[5]=(short)f2bf(b.y); w[6]=(short)f2bf(b.z); w[7]=(short)f2bf(b.w);
  return w;
}

// Persistent pipelined 2-layer LSTM — PLACEMENT-INDEPENDENT.
// 256 WGs x 512 thr, 1 WG/CU, 128 KB LDS combined weights.
// Role from blockIdx.x ONLY: layer = wg>>7, grp = (wg>>5)&3 (32 batch rows),
// slice = wg&31 (16 units). All h/flag traffic device-scope sc1 (L3) so
// correctness holds for ANY workgroup->XCD assignment.
// h0 is FULL-DEPTH [256] (write-once per call): L0 free-runs, zero backpressure,
// no circular waits -> deadlock structurally impossible. Polls carry a 2M-iter
// liveness cap (converts any stall into a fast, diagnosable failure).
__global__ __launch_bounds__(512, 1)
void lstm_persist(const float* __restrict__ text,
                  const float* __restrict__ Wih0, const float* __restrict__ Whh0,
                  const float* __restrict__ bih0, const float* __restrict__ bhh0,
                  const float* __restrict__ Wih1, const float* __restrict__ Whh1,
                  const float* __restrict__ bih1, const float* __restrict__ bhh1,
                  unsigned short* __restrict__ h0x,   // [256][128][512] full depth
                  unsigned short* __restrict__ h1r,   // [4][128][512] ring
                  float* __restrict__ H1f,            // [128][512] final h1 fp32
                  int* __restrict__ F)                // [2][4][256][32] flags
{
  extern __shared__ unsigned short Blds[];   // 64 cols x 1024 k, swizzled, 128 KB
  __shared__ int s_abort;

  const int wg    = blockIdx.x;
  const int layer = wg >> 7;
  const int grp   = (wg >> 5) & 3;
  const int slice = wg & 31;
  const int m0    = grp * 32;
  const int u0    = slice * 16;
  const int tid   = threadIdx.x;
  const int wv    = tid >> 6;
  const int l     = tid & 63;
  const int lj    = l & 15;
  const int lk    = l >> 4;
  const int wgrp  = wv & 3;
  const int mi    = wv >> 2;

  if (tid == 0) s_abort = 0;

  int* F0g = F + (0 + grp) * (TS * 32);        // layer-0 flags, this group
  int* F1g = F + (4 + grp) * (TS * 32);        // layer-1 flags, this group

  // ---- one-time: combined weight slice -> LDS (f32 -> bf16, swizzled) ----
  const float* Wihl = layer ? Wih1 : Wih0;
  const float* Whhl = layer ? Whh1 : Whh0;
  for (int it = tid; it < 64 * 128; it += 512){
    int c = it >> 7, kg = it & 127;
    int unit = u0 + ((c >> 4) << 2) + ((c & 15) >> 2);
    int gate = c & 3;
    const float* s = (kg < 64) ? (Wihl + (size_t)(gate * HD + unit) * HD + kg * 8)
                               : (Whhl + (size_t)(gate * HD + unit) * HD + (kg - 64) * 8);
    *(bf16x8*)((char*)Blds + c * 2048 + ((kg ^ (c & 7)) << 4)) =
        pack8(((const float4*)s)[0], ((const float4*)s)[1]);
  }

  const int myunit = u0 + (wgrp << 2) + (lj >> 2);
  const int mygate = lj & 3;
  const float bgv  = (layer ? bih1 : bih0)[mygate * HD + myunit]
                   + (layer ? bhh1 : bhh0)[mygate * HD + myunit];
  const int aoff   = (m0 + mi * 16 + lj) * HD + lk * 8;   // A element offset (row,k)
  const int cboff  = (wgrp * 16 + lj) * 2048;             // B col byte base in LDS
  const int swz    = lj & 7;

  float cst[4] = {0.f, 0.f, 0.f, 0.f};
  __syncthreads();   // weights staged, s_abort visible

  auto ldsB = [&](int kg)->bf16x8 {
    return *(const bf16x8*)((const char*)Blds + cboff + ((kg ^ swz) << 4));
  };
  // wave-0 poll: lanes 0..31 watch pA[l]; lanes 32..63 watch pB[l-32]. sc1 only.
  // Liveness cap: ~2M iters -> abort (fast wrong answer instead of a hang).
  auto pollwait = [&](const int* pA, const int* pB){
    if (*(volatile int*)&s_abort) return;
    const int* fp = (l < 32) ? (pA + l) : (pB + (l - 32));
    int it = 0;
    for (;;){
      int v = ld_flag_sc1(fp);
      if (__all(v != 0)) break;
      if (++it > 2000000){ s_abort = 1; break; }
      __builtin_amdgcn_s_sleep(1);
    }
  };
  // cell update; packed sc1 h store (dword = 2 units); optional fp32 final write
  auto cellstore = [&](const f32x4& aP, const f32x4& aQ,
                       unsigned short* __restrict__ hslab, bool wrF){
    #pragma unroll
    for (int r = 0; r < 4; ++r){
      float v  = aP[r] + aQ[r] + bgv;
      float v1 = __shfl_xor(v, 1);
      float v2 = __shfl_xor(v, 2);
      float v3 = __shfl_xor(v, 3);
      auto pick = [&](int m)->float {
        return m == 0 ? v : (m == 1 ? v1 : (m == 2 ? v2 : v3));
      };
      float gi = pick(mygate);
      float gf = pick(mygate ^ 1);
      float gg = pick(mygate ^ 2);
      float go = pick(mygate ^ 3);
      float i_ = fsig(gi);
      float f_ = fsig(gf);
      float g_ = ftanh(gg);
      float o_ = fsig(go);
      float c  = f_ * cst[r] + i_ * g_;
      cst[r] = c;
      float h  = o_ * ftanh(c);
      int row  = m0 + mi * 16 + lk * 4 + r;
      int hb   = (int)f2bf(h);
      int pb   = __shfl_xor(hb, 4);          // partner unit (myunit+1)
      if ((lj & 7) == 0)                     // lanes lj in {0,8}: even units
        st_sc1_b32((char*)hslab + ((size_t)row * HD + myunit) * 2,
                   (hb & 0xffff) | (pb << 16));
      if (wrF && mygate == 0)
        H1f[(size_t)row * HD + myunit] = h;
    }
  };
  // L0 input projection: text f32 direct (plain cached, read-only), cvt in-flight
  auto preX = [&](int t, f32x4& acc){
    int ar  = m0 + mi * 16 + lj;
    int b   = ar & 63;
    int ts2 = (ar < 64) ? t : (TS - 1 - t);
    const float* src = text + ((size_t)b * TS + ts2) * HD + lk * 8;
    acc = (f32x4){0.f, 0.f, 0.f, 0.f};
    #pragma unroll
    for (int kk = 0; kk < 16; ++kk){
      const float* s = src + kk * 32;
      bf16x8 a = pack8(((const float4*)s)[0], ((const float4*)s)[1]);
      acc = __builtin_amdgcn_mfma_f32_16x16x32_bf16(a, ldsB(kk * 4 + lk), acc, 0, 0, 0);
    }
  };

  if (layer == 0){
    // ================= layer 0: free-running (no backpressure ever) ==========
    f32x4 accPre;
    preX(0, accPre);
    for (int t = 0; t < TS; ++t){
      if (t > 0){
        if (wv == 0) pollwait(F0g + (t - 1) * 32, F0g + (t - 1) * 32);
        __syncthreads();
      }
      f32x4 accPost = {0.f, 0.f, 0.f, 0.f};
      if (t > 0){
        f32x4 raw[16];
        ld16_sc1(h0x + (size_t)(t - 1) * SLAB + aoff, raw);
        #pragma unroll
        for (int kk = 0; kk < 16; ++kk)
          accPost = __builtin_amdgcn_mfma_f32_16x16x32_bf16(
                      __builtin_bit_cast(bf16x8, raw[kk]), ldsB(64 + kk * 4 + lk),
                      accPost, 0, 0, 0);
      }
      cellstore(accPre, accPost, h0x + (size_t)t * SLAB, false);
      vdrain();                 // sc1 stores acked at coherence point
      __syncthreads();
      if (tid == 0) st_sc1_b32(F0g + t * 32 + slice, 1);
      if (t + 1 < TS) preX(t + 1, accPre);   // off critical path
    }
  } else {
    // ================= layer 1: chases L0 (merged poll, no circular wait) ====
    for (int t = 0; t < TS; ++t){
      if (wv == 0){
        const int* pA = (t > 0) ? (F1g + (t - 1) * 32) : (F0g + 0);
        pollwait(pA, F0g + t * 32);          // peers done t-1  ∥  L0 done t
      }
      __syncthreads();
      f32x4 rawI[16], rawR[16];
      if (t > 0){
        ld16_sc1_issue(h0x + (size_t)t * SLAB + aoff, rawI);
        ld16_sc1(h1r + (size_t)((t - 1) & 3) * SLAB + aoff, rawR);  // drains both
      } else {
        ld16_sc1(h0x + aoff, rawI);
      }
      f32x4 accPre  = {0.f, 0.f, 0.f, 0.f};
      f32x4 accPost = {0.f, 0.f, 0.f, 0.f};
      #pragma unroll
      for (int kk = 0; kk < 16; ++kk)
        accPre = __builtin_amdgcn_mfma_f32_16x16x32_bf16(
                   __builtin_bit_cast(bf16x8, rawI[kk]), ldsB(kk * 4 + lk),
                   accPre, 0, 0, 0);
      if (t > 0){
        #pragma unroll
        for (int kk = 0; kk < 16; ++kk)
          accPost = __builtin_amdgcn_mfma_f32_16x16x32_bf16(
                      __builtin_bit_cast(bf16x8, rawR[kk]), ldsB(64 + kk * 4 + lk),
                      accPost, 0, 0, 0);
      }
      cellstore(accPre, accPost, h1r + (size_t)(t & 3) * SLAB, t == TS - 1);
      vdrain();
      __syncthreads();
      if (tid == 0) st_sc1_b32(F1g + t * 32 + slice, 1);
    }
  }
}

// out[b] = dot(h1_fwd[b], Wlin[0:512]) + dot(h1_rev[b], Wlin[512:1024]) + blin
__global__ void final_linear(const float* __restrict__ H1f, const float* __restrict__ Wlin,
                             const float* __restrict__ blin, float* __restrict__ out){
  int b = blockIdx.x, l = threadIdx.x;
  float s = 0.f;
  for (int j = l; j < HD; j += 64) s += H1f[(size_t)b * HD + j]        * Wlin[j];
  for (int j = l; j < HD; j += 64) s += H1f[(size_t)(NB + b) * HD + j] * Wlin[HD + j];
  #pragma unroll
  for (int off = 32; off; off >>= 1) s += __shfl_down(s, off);
  if (l == 0) out[b] = s + blin[0];
}

extern "C" void kernel_launch(void* const* d_in, const int* in_sizes, int n_in,
                              void* d_out, int out_size, void* d_ws, size_t ws_size,
                              hipStream_t stream)
{
  const float* text = (const float*)d_in[0];
  const float* Wih0 = (const float*)d_in[1];
  const float* Whh0 = (const float*)d_in[2];
  const float* bih0 = (const float*)d_in[3];
  const float* bhh0 = (const float*)d_in[4];
  const float* Wih1 = (const float*)d_in[5];
  const float* Whh1 = (const float*)d_in[6];
  const float* bih1 = (const float*)d_in[7];
  const float* bhh1 = (const float*)d_in[8];
  const float* Wlin = (const float*)d_in[9];
  const float* blin = (const float*)d_in[10];

  // ---- ws layout (~33 MiB) ----
  uint8_t* p = (uint8_t*)d_ws;
  unsigned short* h0x = (unsigned short*)p; p += (size_t)TS * SLAB * 2;     // 32 MiB
  unsigned short* h1r = (unsigned short*)p; p += (size_t)4 * SLAB * 2;      // 512 KiB
  float* H1f          = (float*)p;          p += (size_t)SLAB * 4;          // 256 KiB
  int* F              = (int*)p;            p += (size_t)8 * TS * 32 * 4;   // 256 KiB

  // deterministic init: flags zero at kernel start
  hipMemsetAsync(F, 0, (size_t)8 * TS * 32 * 4, stream);

  hipFuncSetAttribute((const void*)lstm_persist,
                      hipFuncAttributeMaxDynamicSharedMemorySize, 131072);

  const float* A0 = text;
  const float *A1 = Wih0, *A2 = Whh0, *A3 = bih0, *A4 = bhh0;
  const float *A5 = Wih1, *A6 = Whh1, *A7 = bih1, *A8 = bhh1;
  unsigned short* B0 = h0x; unsigned short* B1 = h1r;
  float* B2 = H1f; int* B3 = F;
  void* args[] = {(void*)&A0,
                  (void*)&A1, (void*)&A2, (void*)&A3, (void*)&A4,
                  (void*)&A5, (void*)&A6, (void*)&A7, (void*)&A8,
                  (void*)&B0, (void*)&B1, (void*)&B2, (void*)&B3};
  hipLaunchCooperativeKernel((void*)lstm_persist, dim3(256), dim3(512),
                             args, 131072, stream);

  final_linear<<<NB, 64, 0, stream>>>(H1f, Wlin, blin, (float*)d_out);
}